// Round 6
// baseline (119.667 us; speedup 1.0000x reference)
//
#include <hip/hip_runtime.h>

// Masked cross-attention: out = softmax(where(mask_bool, (Q K^T / 8) * mask_scale, -inf)) V
// B=4, SQ=4096, SK=308, H=8, DH=64. fp32 in/out, f16 MFMA internally.
//
// R6: occupancy fix. LDS eliminated: K/V pre-transformed once (prep kernel) into
// f16 MFMA-fragment layout in d_ws (2.6 MB, L2-resident, reused by 64 WGs each).
// Main kernel: 256-thr WGs, zero LDS, zero barriers, 1 wave per 16 q-rows; K-frag
// = one 16B load, V-frag = one 8B load from L2. Numerics verbatim R5 (proven).

#define NB     4
#define NSQ    4096
#define NSK    308
#define NH     8
#define NDH    64
#define NINNER 512
#define NKT    20            // ceil(308/16)
#define NTHREADS 256
#define PF     4             // mask prefetch depth

#define KFRAG_PER_BH (NKT*2*64*8)   // 20480 f16 per (b,h)
#define VFRAG_PER_BH (NKT*4*64*4)   // 20480 f16 per (b,h)
#define WS_BYTES ((size_t)(NB*NH) * (KFRAG_PER_BH + VFRAG_PER_BH) * 2)  // 2.62 MB

typedef _Float16 h8 __attribute__((ext_vector_type(8)));
typedef _Float16 h4 __attribute__((ext_vector_type(4)));
typedef float    f4 __attribute__((ext_vector_type(4)));
typedef int      i4 __attribute__((ext_vector_type(4)));

// ---- prep: K,V (f32, row-major) -> f16 MFMA-fragment arrays in ws ----
// Same index math as R5's proven LDS staging, targets global.
__global__ __launch_bounds__(512) void omost_prep(
    const float* __restrict__ Kg, const float* __restrict__ Vg,
    _Float16* __restrict__ ws)
{
  const int bh  = blockIdx.x;
  const int b   = bh >> 3;
  const int h   = bh & 7;
  const int tid = threadIdx.x;

  _Float16* Kfrag = ws + (size_t)bh * KFRAG_PER_BH;
  _Float16* Vfrag = ws + (size_t)(NB*NH) * KFRAG_PER_BH + (size_t)bh * VFRAG_PER_BH;

  // K slots s=(kt,dhc,l): K[kt*16+(l&15)][dhc*32+(l>>4)*8 + 0..7]
  const float* Kb = Kg + (size_t)b * NSK * NINNER + h * NDH;
  #pragma unroll
  for (int i = 0; i < (NKT*2*64) / 512; ++i) {   // 5 iters
    int s   = tid + i * 512;
    int l   = s & 63;
    int dhc = (s >> 6) & 1;
    int kt  = s >> 7;
    int row = kt * 16 + (l & 15);
    int col = dhc * 32 + ((l >> 4) << 3);
    h8 hk;
    #pragma unroll
    for (int j = 0; j < 8; ++j) hk[j] = (_Float16)0.f;
    if (row < NSK) {
      const float* p = Kb + (size_t)row * NINNER + col;
      f4 a = *(const f4*)p;
      f4 c = *(const f4*)(p + 4);
      hk[0]=(_Float16)a[0]; hk[1]=(_Float16)a[1]; hk[2]=(_Float16)a[2]; hk[3]=(_Float16)a[3];
      hk[4]=(_Float16)c[0]; hk[5]=(_Float16)c[1]; hk[6]=(_Float16)c[2]; hk[7]=(_Float16)c[3];
    }
    *(h8*)(Kfrag + (size_t)s * 8) = hk;
  }

  // V slots s=(kt,nt,l): V[kt*16+(l>>4)*4 + 0..3][nt*16+(l&15)]
  const float* Vb = Vg + (size_t)b * NSK * NINNER + h * NDH;
  #pragma unroll
  for (int i = 0; i < (NKT*4*64) / 512; ++i) {   // 10 iters
    int s    = tid + i * 512;
    int l    = s & 63;
    int nt   = (s >> 6) & 3;
    int kt   = s >> 8;
    int col  = nt * 16 + (l & 15);
    int row0 = kt * 16 + ((l >> 4) << 2);
    h4 hv;
    #pragma unroll
    for (int j = 0; j < 4; ++j) hv[j] = (_Float16)0.f;
    #pragma unroll
    for (int j = 0; j < 4; ++j) {
      int row = row0 + j;
      if (row < NSK) hv[j] = (_Float16)Vb[(size_t)row * NINNER + col];
    }
    *(h4*)(Vfrag + (size_t)s * 4) = hv;
  }
}

// ---- main: no LDS, no barriers; 1 wave per 16 q-rows ----
__global__ __launch_bounds__(NTHREADS) void omost_attn(
    const float* __restrict__ Qg, const float* __restrict__ MSg,
    const int*   __restrict__ MBg, const _Float16* __restrict__ ws,
    float* __restrict__ Og)
{
  const int tid  = threadIdx.x;
  const int lane = tid & 63;
  const int wv   = tid >> 6;      // wave 0..3
  const int lg   = lane >> 4;     // lane group 0..3
  const int lr   = lane & 15;

  const int wg = blockIdx.x;
  const int qt = wg & (NSQ / 64 - 1);   // 0..63
  const int bh = wg >> 6;
  const int b  = bh >> 3;
  const int h  = bh & 7;

  const int q0   = qt * 64 + wv * 16;
  const int qrow = q0 + lr;
  const size_t mrow = ((size_t)bh * NSQ + qrow) * NSK;   // 16B-aligned (308%4==0)

  const h8* Kf = (const h8*)(ws + (size_t)bh * KFRAG_PER_BH);
  const h4* Vf = (const h4*)(ws + (size_t)(NB*NH) * KFRAG_PER_BH + (size_t)bh * VFRAG_PER_BH);

  // ---- issue first PF mask tiles early ----
  f4 msb[PF];
  i4 mbb[PF];
  #pragma unroll
  for (int d = 0; d < PF; ++d) {            // kb max = 60 < 304: no clamp
    int kb = d * 16 + lg * 4;
    msb[d] = *(const f4*)(MSg + mrow + kb);
    mbb[d] = *(const i4*)(MBg + mrow + kb);
  }

  const float NEG_INF = -__builtin_inff();

  // ---- per-wave Q fragments ----
  // lane holds Q[q0 + (lane&15)][dhc*32 + (lane>>4)*8 + 0..7]
  const float* Qb = Qg + ((size_t)b * NSQ + qrow) * NINNER + h * NDH;
  h8 qf[2];
  #pragma unroll
  for (int dhc = 0; dhc < 2; ++dhc) {
    const float* p = Qb + dhc * 32 + lg * 8;
    f4 a = *(const f4*)p;
    f4 c = *(const f4*)(p + 4);
    h8 t;
    t[0]=(_Float16)a[0]; t[1]=(_Float16)a[1]; t[2]=(_Float16)a[2]; t[3]=(_Float16)a[3];
    t[4]=(_Float16)c[0]; t[5]=(_Float16)c[1]; t[6]=(_Float16)c[2]; t[7]=(_Float16)c[3];
    qf[dhc] = t;
  }

  // ---- fused QK^T + mask loop (prefetched masks), scores in registers ----
  // S^T lane layout: q = q0+(l&15), k = kt*16 + (l>>4)*4 + r
  f4 S[NKT];
  float rmax = NEG_INF;
  #pragma unroll
  for (int kt = 0; kt < NKT; ++kt) {
    f4 ms = msb[kt % PF];
    i4 mb = mbb[kt % PF];
    if (kt + PF < NKT) {                    // prefetch PF tiles ahead (clamped)
      int kb  = (kt + PF) * 16 + lg * 4;
      int kbl = kb > (NSK - 4) ? (NSK - 4) : kb;
      msb[(kt + PF) % PF] = *(const f4*)(MSg + mrow + kbl);
      mbb[(kt + PF) % PF] = *(const i4*)(MBg + mrow + kbl);
    }
    f4 c = {0.f, 0.f, 0.f, 0.f};
    c = __builtin_amdgcn_mfma_f32_16x16x32_f16(Kf[(kt*2+0)*64 + lane], qf[0], c, 0, 0, 0);
    c = __builtin_amdgcn_mfma_f32_16x16x32_f16(Kf[(kt*2+1)*64 + lane], qf[1], c, 0, 0, 0);

    const int kb0 = kt * 16 + lg * 4;
    f4 s;
    #pragma unroll
    for (int r = 0; r < 4; ++r) {
      bool ok = (kb0 + r < NSK) && (mb[r] != 0);
      s[r] = ok ? c[r] * 0.125f * ms[r] : NEG_INF;
      rmax = fmaxf(rmax, s[r]);
    }
    S[kt] = s;
  }

  // ---- softmax (R5-verbatim): true max, exp, sum, normalize before PV ----
  rmax = fmaxf(rmax, __shfl_xor(rmax, 16, 64));
  rmax = fmaxf(rmax, __shfl_xor(rmax, 32, 64));
  float ssum = 0.f;
  #pragma unroll
  for (int kt = 0; kt < NKT; ++kt) {
    f4 s = S[kt];
    #pragma unroll
    for (int r = 0; r < 4; ++r) { float p = __expf(s[r] - rmax); s[r] = p; ssum += p; }
    S[kt] = s;
  }
  ssum += __shfl_xor(ssum, 16, 64);
  ssum += __shfl_xor(ssum, 32, 64);
  const float inv = 1.f / ssum;

  // ---- O = P · V : P's C-layout == A-layout of 16x16x16 f16 MFMA ----
  f4 acc[4];
  #pragma unroll
  for (int nt = 0; nt < 4; ++nt) acc[nt] = (f4){0.f, 0.f, 0.f, 0.f};
  #pragma unroll
  for (int kt = 0; kt < NKT; ++kt) {
    h4 pa;
    #pragma unroll
    for (int r = 0; r < 4; ++r) pa[r] = (_Float16)(S[kt][r] * inv);
    #pragma unroll
    for (int nt = 0; nt < 4; ++nt)
      acc[nt] = __builtin_amdgcn_mfma_f32_16x16x16f16(pa, Vf[(kt*4+nt)*64 + lane], acc[nt], 0, 0, 0);
  }

  // ---- store: lane holds O[q0 + (l>>4)*4 + r][nt*16 + (l&15)] ----
  float* Ob = Og + (size_t)b * NSQ * NINNER + h * NDH;
  #pragma unroll
  for (int nt = 0; nt < 4; ++nt) {
    #pragma unroll
    for (int r = 0; r < 4; ++r) {
      int qq = q0 + lg * 4 + r;
      Ob[(size_t)qq * NINNER + nt * 16 + lr] = acc[nt][r];
    }
  }
}

extern "C" void kernel_launch(void* const* d_in, const int* in_sizes, int n_in,
                              void* d_out, int out_size, void* d_ws, size_t ws_size,
                              hipStream_t stream) {
  const float* Qg  = (const float*)d_in[0];
  const float* Kg  = (const float*)d_in[1];
  const float* Vg  = (const float*)d_in[2];
  const float* MSg = (const float*)d_in[3];
  const int*   MBg = (const int*)d_in[4];
  float* Og = (float*)d_out;
  _Float16* ws = (_Float16*)d_ws;

  if (ws_size < WS_BYTES) return;   // loud failure (output stays zeroed) over OOB writes

  omost_prep<<<dim3(NB*NH), dim3(512), 0, stream>>>(Kg, Vg, ws);

  const int nwg = NB * NH * (NSQ / 64);   // 2048
  omost_attn<<<dim3(nwg), dim3(NTHREADS), 0, stream>>>(Qg, MSg, MBg, ws, Og);
}